// Round 4
// baseline (901.799 us; speedup 1.0000x reference)
//
#include <hip/hip_runtime.h>
#include <hip/hip_bf16.h>
#include <stdint.h>

typedef __bf16 bf16;
typedef __bf16 bf16x8 __attribute__((ext_vector_type(8)));
typedef float f32x4 __attribute__((ext_vector_type(4)));
typedef unsigned short u16;
typedef unsigned short u16x4 __attribute__((ext_vector_type(4)));

// B=8, S=1024, H=16, D=64, LAT=DV=1024, M=B*S=8192
// fp32 inputs -> bf16 internal MFMA -> fp32 output.

__device__ __forceinline__ void gld16(const bf16* g, bf16* l) {
    __builtin_amdgcn_global_load_lds(
        (const __attribute__((address_space(1))) void*)g,
        (__attribute__((address_space(3))) void*)l, 16, 0, 0);
}

// ---------------------------------------------------------------------------
// prep: fused {fp32->bf16 convert of input/latent} + {4x weight transpose}.
// bid < 4096: convert (2048 blocks per tensor); bid >= 4096: transpose.
// ---------------------------------------------------------------------------
__global__ __launch_bounds__(256) void prep(
        const float* __restrict__ input, const float* __restrict__ latent,
        bf16* __restrict__ Xb, bf16* __restrict__ Lb,
        const float* __restrict__ w0, const float* __restrict__ w1,
        const float* __restrict__ w2, const float* __restrict__ w3,
        bf16* __restrict__ t0, bf16* __restrict__ t1,
        bf16* __restrict__ t2, bf16* __restrict__ t3) {
    __shared__ float tile[32][33];
    const int bid = blockIdx.x;
    const int tid = threadIdx.x;
    if (bid < 4096) {
        const float* src = (bid >> 11) ? latent : input;
        bf16* dst = (bid >> 11) ? Lb : Xb;
        const int nchunk = (8 * 1024 * 1024) / 4;
        for (int c = (bid & 2047) * 256 + tid; c < nchunk; c += 2048 * 256) {
            float4 v = *(const float4*)&src[(size_t)c * 4];
            u16x4 o;
            o[0] = __builtin_bit_cast(u16, (bf16)v.x);
            o[1] = __builtin_bit_cast(u16, (bf16)v.y);
            o[2] = __builtin_bit_cast(u16, (bf16)v.z);
            o[3] = __builtin_bit_cast(u16, (bf16)v.w);
            *(u16x4*)&dst[(size_t)c * 4] = o;
        }
    } else {
        const int tb = bid - 4096;
        const float* src; bf16* dst;
        switch (tb >> 10) {
            case 0:  src = w0; dst = t0; break;
            case 1:  src = w1; dst = t1; break;
            case 2:  src = w2; dst = t2; break;
            default: src = w3; dst = t3; break;
        }
        const int r  = tb & 1023;
        const int bx = r & 31, by = r >> 5;
        const int tx = tid & 31, ty = tid >> 5;   // (32, 8)
        const int x = bx * 32 + tx;
        const int y = by * 32 + ty;
        #pragma unroll
        for (int j = 0; j < 32; j += 8)
            tile[ty + j][tx] = src[(size_t)(y + j) * 1024 + x];
        __syncthreads();
        const int x2 = by * 32 + tx;
        const int y2 = bx * 32 + ty;
        #pragma unroll
        for (int j = 0; j < 32; j += 8)
            dst[(size_t)(y2 + j) * 1024 + x2] = (bf16)tile[tx][ty + j];
    }
}

// ---------------------------------------------------------------------------
// GEMM core: C[m][n] = sum_k X[m][k]*Wt[n][k] + bias[n].  128x128 tile, BK=32,
// global_load_lds staging, XOR-swizzled 64B rows (2-way-free b128 reads).
// MODE 0: fp32 [M][N];  MODE 1: bf16 [bh][s][64];  MODE 2: bf16 [bh][64][s]
// ---------------------------------------------------------------------------
template<int MODE>
__device__ __forceinline__ void gemm_core(const bf16* __restrict__ X,
                                          const bf16* __restrict__ Wt,
                                          const float* __restrict__ bias,
                                          void* __restrict__ outv,
                                          int m0, int n0, bf16* Al, bf16* Bl) {
    const int tid  = threadIdx.x;
    const int lane = tid & 63;
    const int w    = tid >> 6;
    const int wm   = (w & 1) * 64;
    const int wn   = (w >> 1) * 64;
    const int l15  = lane & 15;
    const int quad = lane >> 4;
    const int sw   = (l15 >> 1) & 3;   // read-side XOR swizzle

    f32x4 acc[4][4] = {};

    for (int kt = 0; kt < 1024; kt += 32) {
        __syncthreads();
        #pragma unroll
        for (int t = 0; t < 2; t++) {
            int c = (w * 2 + t) * 64 + lane;       // chunk 0..511
            int row = c >> 2;
            int e   = (c & 3) ^ ((c >> 3) & 3);    // swizzled dword-quad
            gld16(&X [(size_t)(m0 + row) * 1024 + kt + e * 8], &Al[(w * 2 + t) * 512]);
            gld16(&Wt[(size_t)(n0 + row) * 1024 + kt + e * 8], &Bl[(w * 2 + t) * 512]);
        }
        __syncthreads();
        bf16x8 a[4], b[4];
        #pragma unroll
        for (int i = 0; i < 4; i++)
            a[i] = *(const bf16x8*)&Al[(wm + i * 16 + l15) * 32 + (quad ^ sw) * 8];
        #pragma unroll
        for (int j = 0; j < 4; j++)
            b[j] = *(const bf16x8*)&Bl[(wn + j * 16 + l15) * 32 + (quad ^ sw) * 8];
        #pragma unroll
        for (int i = 0; i < 4; i++)
            #pragma unroll
            for (int j = 0; j < 4; j++)
                acc[i][j] = __builtin_amdgcn_mfma_f32_16x16x32_bf16(a[i], b[j], acc[i][j], 0, 0, 0);
    }

    float bv[4];
    #pragma unroll
    for (int j = 0; j < 4; j++) bv[j] = bias[n0 + wn + j * 16 + l15];

    #pragma unroll
    for (int i = 0; i < 4; i++) {
        int mbase = m0 + wm + i * 16 + quad * 4;
        #pragma unroll
        for (int j = 0; j < 4; j++) {
            int n = n0 + wn + j * 16 + l15;
            if (MODE == 2) {
                bf16* out = (bf16*)outv;
                int b = mbase >> 10, s = mbase & 1023;
                int h = n >> 6, d = n & 63;
                u16x4 pack;
                #pragma unroll
                for (int r = 0; r < 4; r++) {
                    bf16 v = (bf16)(acc[i][j][r] + bv[j]);
                    pack[r] = __builtin_bit_cast(u16, v);
                }
                *(u16x4*)&out[(((size_t)(b * 16 + h)) * 64 + d) * 1024 + s] = pack;
            } else if (MODE == 1) {
                bf16* out = (bf16*)outv;
                #pragma unroll
                for (int r = 0; r < 4; r++) {
                    int m = mbase + r;
                    int b = m >> 10, s = m & 1023;
                    int h = n >> 6, d = n & 63;
                    out[(((size_t)(b * 16 + h)) * 1024 + s) * 64 + d] =
                        (bf16)(acc[i][j][r] + bv[j]);
                }
            } else {
                float* out = (float*)outv;
                #pragma unroll
                for (int r = 0; r < 4; r++)
                    out[(size_t)(mbase + r) * 1024 + n] = acc[i][j][r] + bv[j];
            }
        }
    }
}

// Fused Q/K/V projections, compile-time epilogues: z=0 Q, z=1 K, z=2 V.
__global__ __launch_bounds__(256) void gemm_qkv(
        const bf16* __restrict__ Lb, const bf16* __restrict__ Xb,
        const bf16* __restrict__ Wqt, const bf16* __restrict__ Wkt,
        const bf16* __restrict__ Wvt,
        const float* __restrict__ bq, const float* __restrict__ bk,
        const float* __restrict__ bv,
        bf16* __restrict__ Qh, bf16* __restrict__ Kh, bf16* __restrict__ Vt) {
    __shared__ bf16 Al[128 * 32];
    __shared__ bf16 Bl[128 * 32];
    const int m0 = blockIdx.x * 128, n0 = blockIdx.y * 128;
    if (blockIdx.z == 0)      gemm_core<1>(Lb, Wqt, bq, Qh, m0, n0, Al, Bl);
    else if (blockIdx.z == 1) gemm_core<1>(Xb, Wkt, bk, Kh, m0, n0, Al, Bl);
    else                      gemm_core<2>(Xb, Wvt, bv, Vt, m0, n0, Al, Bl);
}

// Output projection (fp32 out)
__global__ __launch_bounds__(256) void gemm_o(
        const bf16* __restrict__ Ob, const bf16* __restrict__ Wot,
        const float* __restrict__ bo, float* __restrict__ out) {
    __shared__ bf16 Al[128 * 32];
    __shared__ bf16 Bl[128 * 32];
    gemm_core<0>(Ob, Wot, bo, out, blockIdx.x * 128, blockIdx.y * 128, Al, Bl);
}

// ---------------------------------------------------------------------------
// Flash attention, SWAPPED QK^T (T12), fixed-max softmax, deferred denom.
// Q,K: [bh][1024][64].  Vt: [bh][64][1024].  mask: [bh][1024][1024] i32.
// 1024 blocks (XCD-swizzled), 4 waves x 32 q-rows; 64 keys/iter, 16 iters.
//
// S^T = mfma(A=K_frag, B=Q_frag): output lane holds col=l15=q-row,
// row=quad*4+r=key.  This makes the per-lane score row LANE-LOCAL in q:
//  - mask:   one int4 per (rb,t)  (8 dwordx4/iter, was 32 scalar dwords)
//  - P store: one ds_write_b64 per (rb,t) into row-major P[q][key]
//             (8 b64/iter, was 32 scalar b16) -- PV read side UNCHANGED
//  - lsum:   2 regs, quad-reduce (2 shfl) + 8 epilogue bpermutes
// K/V frags already match the A/B lane mapping, so staging is unchanged.
//
// Pipeline (T4): K/V triple-buffered, DMA 2 iters ahead; per-iter sync is
// s_waitcnt vmcnt(8) + raw s_barrier + sched_barrier(0).  Per-iter issue:
// [mask(it+1) 8 dwordx4] then [DMA(it+2) 8] -> at barrier the oldest-first
// vmcnt(8) retires {mask(it), DMA(it)} and floats DMA(it+1)'s 8 across.
// ---------------------------------------------------------------------------
__global__ __launch_bounds__(256, 2) void attn(const bf16* __restrict__ Q,
                                               const bf16* __restrict__ K,
                                               const bf16* __restrict__ Vt,
                                               const int*  __restrict__ mask,
                                               bf16* __restrict__ O) {
    __shared__ bf16 Kl[3][4096];     // [buf][key][64 d], 128B rows, swizzled
    __shared__ bf16 Vl[3][4096];     // [buf][d][64 k],   128B rows, swizzled
    __shared__ bf16 Pl[4][32 * 68];  // per-wave P [32 q][64 k], stride 68

    const int tid  = threadIdx.x;
    const int lane = tid & 63;
    const int w    = tid >> 6;
    const int l15  = lane & 15;
    const int quad = lane >> 4;

    // XCD-aware: blk&7 = xcd (presumed rr dispatch); 16 heads per xcd.
    const int blk = blockIdx.x;
    const int bh  = (blk & 7) * 16 + (blk >> 6);
    const int q0  = ((blk >> 3) & 7) * 128;
    const int qrow0 = q0 + w * 32;

    const bf16* Kbh = K  + (size_t)bh * 65536;
    const bf16* Vbh = Vt + (size_t)bh * 65536;
    // swapped layout: lane (quad,l15) reads mask row (qrow0+rb*16+l15),
    // cols kn + t*16 + quad*4 .. +3  -> int4
    const int* mbase = mask + ((size_t)bh * 1024 + qrow0 + l15) * 1024 + quad * 4;

    const int c0 = (w * 2 + 0) * 64 + lane;   // staging chunks (512 per tensor)
    const int c1 = (w * 2 + 1) * 64 + lane;
    const int swz = l15 & 7;                  // read-side XOR swizzle

    #define STAGE_KV(kk, buf)                                                          \
        {                                                                              \
            int r0 = c0 >> 3, e0 = (c0 & 7) ^ (r0 & 7);                                \
            int r1 = c1 >> 3, e1 = (c1 & 7) ^ (r1 & 7);                                \
            gld16(&Kbh[(size_t)((kk) + r0) * 64 + e0 * 8], &Kl[buf][(w * 2 + 0) * 512]); \
            gld16(&Kbh[(size_t)((kk) + r1) * 64 + e1 * 8], &Kl[buf][(w * 2 + 1) * 512]); \
            gld16(&Vbh[(size_t)r0 * 1024 + (kk) + e0 * 8], &Vl[buf][(w * 2 + 0) * 512]); \
            gld16(&Vbh[(size_t)r1 * 1024 + (kk) + e1 * 8], &Vl[buf][(w * 2 + 1) * 512]); \
        }

    // prologue (issue order matters for the counted waits):
    // [qa 4] [DMA(0) 8] [mask(0) 8] [DMA(1) 8]  -> barrier(0) vmcnt(8)
    bf16x8 qa[2][2];
    #pragma unroll
    for (int rb = 0; rb < 2; rb++) {
        const bf16* Qb = Q + ((size_t)bh * 1024 + qrow0 + rb * 16 + l15) * 64;
        qa[rb][0] = *(const bf16x8*)&Qb[quad * 8];
        qa[rb][1] = *(const bf16x8*)&Qb[32 + quad * 8];
    }
    STAGE_KV(0, 0);
    int4 mn4[2][4];
    #pragma unroll
    for (int rb = 0; rb < 2; rb++)
        #pragma unroll
        for (int t = 0; t < 4; t++)
            mn4[rb][t] = *(const int4*)&mbase[rb * 16 * 1024 + t * 16];
    STAGE_KV(64, 1);

    f32x4 o[2][4] = {};
    float lsum[2] = {};
    bf16* Pw = Pl[w];
    int cur = 0, stg = 2;

    for (int it = 0; it < 16; it++) {
        // counted-vmcnt barrier: retire DMA(it)+mask(it), float DMA(it+1)
        asm volatile("s_waitcnt vmcnt(8)" ::: "memory");
        __builtin_amdgcn_s_barrier();
        __builtin_amdgcn_sched_barrier(0);

        // compress arrived mask to nibbles (bit r), freeing prefetch regs
        int nib[2][4];
        #pragma unroll
        for (int rb = 0; rb < 2; rb++)
            #pragma unroll
            for (int t = 0; t < 4; t++)
                nib[rb][t] = (mn4[rb][t].x != 0) | ((mn4[rb][t].y != 0) << 1) |
                             ((mn4[rb][t].z != 0) << 2) | ((mn4[rb][t].w != 0) << 3);

        // mask prefetch for it+1 FIRST (wrapped on last iter: unused)
        {
            const int kn1 = ((it + 1) & 15) * 64;
            #pragma unroll
            for (int rb = 0; rb < 2; rb++)
                #pragma unroll
                for (int t = 0; t < 4; t++)
                    mn4[rb][t] = *(const int4*)&mbase[rb * 16 * 1024 + kn1 + t * 16];
        }
        // then K/V DMA for it+2 (wrapped on last two iters: unused)
        STAGE_KV(((it + 2) & 15) * 64, stg);

        const bf16* Kc = Kl[cur];
        const bf16* Vc = Vl[cur];

        // swapped QK^T: S^T[key][q] tiles; K-frag is A, Q-frag is B.
        f32x4 s[2][4];
        __builtin_amdgcn_s_setprio(1);
        #pragma unroll
        for (int t = 0; t < 4; t++) {
            bf16x8 kb0 = *(const bf16x8*)&Kc[(t * 16 + l15) * 64 + ((0 + quad) ^ swz) * 8];
            bf16x8 kb1 = *(const bf16x8*)&Kc[(t * 16 + l15) * 64 + ((4 + quad) ^ swz) * 8];
            #pragma unroll
            for (int rb = 0; rb < 2; rb++) {
                f32x4 z = {};
                z = __builtin_amdgcn_mfma_f32_16x16x32_bf16(kb0, qa[rb][0], z, 0, 0, 0);
                z = __builtin_amdgcn_mfma_f32_16x16x32_bf16(kb1, qa[rb][1], z, 0, 0, 0);
                s[rb][t] = z;
            }
        }
        __builtin_amdgcn_s_setprio(0);

        // p = exp2(s*0.125*log2e - 12*log2e)  == exp(s/8 - 12)
        // lane holds q-row l15, keys t*16+quad*4+r -> b64 P-row stores
        #pragma unroll
        for (int rb = 0; rb < 2; rb++)
            #pragma unroll
            for (int t = 0; t < 4; t++) {
                u16x4 pk;
                #pragma unroll
                for (int r = 0; r < 4; r++) {
                    float p = exp2f(fmaf(s[rb][t][r], 0.1803368801111204f,
                                         -17.312340490667565f));
                    p = ((nib[rb][t] >> r) & 1) ? p : 0.0f;
                    lsum[rb] += p;
                    pk[r] = __builtin_bit_cast(u16, (bf16)p);
                }
                *(u16x4*)&Pw[(rb * 16 + l15) * 68 + t * 16 + quad * 4] = pk;
            }

        // PV: P row-major [q][key] -> A-frag b128 reads (unchanged layout)
        bf16x8 pa[2][2];
        #pragma unroll
        for (int rb = 0; rb < 2; rb++) {
            pa[rb][0] = *(const bf16x8*)&Pw[(rb * 16 + l15) * 68 + quad * 8];
            pa[rb][1] = *(const bf16x8*)&Pw[(rb * 16 + l15) * 68 + 32 + quad * 8];
        }
        __builtin_amdgcn_s_setprio(1);
        #pragma unroll
        for (int nt = 0; nt < 4; nt++) {
            bf16x8 vb0 = *(const bf16x8*)&Vc[(nt * 16 + l15) * 64 + ((0 + quad) ^ swz) * 8];
            bf16x8 vb1 = *(const bf16x8*)&Vc[(nt * 16 + l15) * 64 + ((4 + quad) ^ swz) * 8];
            #pragma unroll
            for (int rb = 0; rb < 2; rb++) {
                o[rb][nt] = __builtin_amdgcn_mfma_f32_16x16x32_bf16(pa[rb][0], vb0, o[rb][nt], 0, 0, 0);
                o[rb][nt] = __builtin_amdgcn_mfma_f32_16x16x32_bf16(pa[rb][1], vb1, o[rb][nt], 0, 0, 0);
            }
        }
        __builtin_amdgcn_s_setprio(0);

        cur = (cur == 2) ? 0 : cur + 1;
        stg = (stg == 2) ? 0 : stg + 1;
    }
    #undef STAGE_KV

    // epilogue: quad-reduce denominators (q-row = l15), redistribute to the
    // C-layout rows (q-row = quad*4+r) via shfl, normalize, write.
    const int b = bh >> 4, h = bh & 15;
    #pragma unroll
    for (int rb = 0; rb < 2; rb++) {
        float l = lsum[rb];
        l += __shfl_xor(l, 16, 64);
        l += __shfl_xor(l, 32, 64);
        float inv = 1.0f / l;
        #pragma unroll
        for (int r = 0; r < 4; r++) {
            float invr = __shfl(inv, (lane & 48) | (quad * 4 + r), 64);
            int srow = qrow0 + rb * 16 + quad * 4 + r;
            bf16* orow = O + ((size_t)(b * 1024 + srow)) * 1024 + h * 64;
            #pragma unroll
            for (int nt = 0; nt < 4; nt++)
                orow[nt * 16 + l15] = (bf16)(o[rb][nt][r] * invr);
        }
    }
}

// ---------------------------------------------------------------------------
extern "C" void kernel_launch(void* const* d_in, const int* in_sizes, int n_in,
                              void* d_out, int out_size, void* d_ws, size_t ws_size,
                              hipStream_t stream) {
    const float* input  = (const float*)d_in[0];
    const float* latent = (const float*)d_in[1];
    const int*   mask   = (const int*)d_in[2];
    const float* Wq = (const float*)d_in[3];
    const float* bq = (const float*)d_in[4];
    const float* Wk = (const float*)d_in[5];
    const float* bk = (const float*)d_in[6];
    const float* Wv = (const float*)d_in[7];
    const float* bv = (const float*)d_in[8];
    const float* Wo = (const float*)d_in[9];
    const float* bo = (const float*)d_in[10];
    float* out = (float*)d_out;

    char* ws = (char*)d_ws;
    bf16* Xb  = (bf16*)(ws);                      // 16 MB  input  bf16
    bf16* Lb  = (bf16*)(ws + (16u << 20));        // 16 MB  latent bf16
    bf16* Qh  = (bf16*)(ws + (32u << 20));        // 16 MB  [bh][s][64]
    bf16* Kh  = (bf16*)(ws + (48u << 20));        // 16 MB  [bh][s][64]
    bf16* Vt  = (bf16*)(ws + (64u << 20));        // 16 MB  [bh][64][s]
    bf16* Ob  = (bf16*)(ws + (80u << 20));        // 16 MB  [8192][1024]
    bf16* Wqt = (bf16*)(ws + (96u << 20));
    bf16* Wkt = (bf16*)(ws + (98u << 20));
    bf16* Wvt = (bf16*)(ws + (100u << 20));
    bf16* Wot = (bf16*)(ws + (102u << 20));

    // fused convert + weight transpose
    prep<<<dim3(8192, 1, 1), 256, 0, stream>>>(
        input, latent, Xb, Lb, Wq, Wk, Wv, Wo, Wqt, Wkt, Wvt, Wot);

    // fused Q/K/V projection GEMMs (compile-time epilogues)
    gemm_qkv<<<dim3(64, 8, 3), 256, 0, stream>>>(
        Lb, Xb, Wqt, Wkt, Wvt, bq, bk, bv, Qh, Kh, Vt);

    attn<<<dim3(1024, 1, 1), 256, 0, stream>>>(Qh, Kh, Vt, mask, Ob);

    gemm_o<<<dim3(64, 8, 1), 256, 0, stream>>>(Ob, Wot, bo, out);
}

// Round 5
// 894.622 us; speedup vs baseline: 1.0080x; 1.0080x over previous
//
#include <hip/hip_runtime.h>
#include <hip/hip_bf16.h>
#include <stdint.h>

typedef __bf16 bf16;
typedef __bf16 bf16x8 __attribute__((ext_vector_type(8)));
typedef float f32x4 __attribute__((ext_vector_type(4)));
typedef unsigned short u16;
typedef unsigned short u16x4 __attribute__((ext_vector_type(4)));

// B=8, S=1024, H=16, D=64, LAT=DV=1024, M=B*S=8192
// fp32 inputs -> bf16 internal MFMA -> fp32 output.

__device__ __forceinline__ void gld16(const bf16* g, bf16* l) {
    __builtin_amdgcn_global_load_lds(
        (const __attribute__((address_space(1))) void*)g,
        (__attribute__((address_space(3))) void*)l, 16, 0, 0);
}

// ---------------------------------------------------------------------------
// prep: fused {fp32->bf16 convert of input/latent} + {4x weight transpose}.
// bid < 4096: convert (2048 blocks per tensor); bid >= 4096: transpose.
// ---------------------------------------------------------------------------
__global__ __launch_bounds__(256) void prep(
        const float* __restrict__ input, const float* __restrict__ latent,
        bf16* __restrict__ Xb, bf16* __restrict__ Lb,
        const float* __restrict__ w0, const float* __restrict__ w1,
        const float* __restrict__ w2, const float* __restrict__ w3,
        bf16* __restrict__ t0, bf16* __restrict__ t1,
        bf16* __restrict__ t2, bf16* __restrict__ t3) {
    __shared__ float tile[32][33];
    const int bid = blockIdx.x;
    const int tid = threadIdx.x;
    if (bid < 4096) {
        const float* src = (bid >> 11) ? latent : input;
        bf16* dst = (bid >> 11) ? Lb : Xb;
        const int nchunk = (8 * 1024 * 1024) / 4;
        for (int c = (bid & 2047) * 256 + tid; c < nchunk; c += 2048 * 256) {
            float4 v = *(const float4*)&src[(size_t)c * 4];
            u16x4 o;
            o[0] = __builtin_bit_cast(u16, (bf16)v.x);
            o[1] = __builtin_bit_cast(u16, (bf16)v.y);
            o[2] = __builtin_bit_cast(u16, (bf16)v.z);
            o[3] = __builtin_bit_cast(u16, (bf16)v.w);
            *(u16x4*)&dst[(size_t)c * 4] = o;
        }
    } else {
        const int tb = bid - 4096;
        const float* src; bf16* dst;
        switch (tb >> 10) {
            case 0:  src = w0; dst = t0; break;
            case 1:  src = w1; dst = t1; break;
            case 2:  src = w2; dst = t2; break;
            default: src = w3; dst = t3; break;
        }
        const int r  = tb & 1023;
        const int bx = r & 31, by = r >> 5;
        const int tx = tid & 31, ty = tid >> 5;   // (32, 8)
        const int x = bx * 32 + tx;
        const int y = by * 32 + ty;
        #pragma unroll
        for (int j = 0; j < 32; j += 8)
            tile[ty + j][tx] = src[(size_t)(y + j) * 1024 + x];
        __syncthreads();
        const int x2 = by * 32 + tx;
        const int y2 = bx * 32 + ty;
        #pragma unroll
        for (int j = 0; j < 32; j += 8)
            dst[(size_t)(y2 + j) * 1024 + x2] = (bf16)tile[tx][ty + j];
    }
}

// ---------------------------------------------------------------------------
// GEMM core: C[m][n] = sum_k X[m][k]*Wt[n][k] + bias[n].  128x128 tile,
// BK=64 (this round: halves barrier/vmcnt-drain count vs BK=32 at unchanged
// occupancy -- LDS 32KB, VGPR still the 3-blocks/CU cap).  128B LDS rows
// with the same XOR dword-quad swizzle proven in attn's STAGE_KV path.
// MODE 0: fp32 [M][N];  MODE 1: bf16 [bh][s][64];  MODE 2: bf16 [bh][64][s]
// ---------------------------------------------------------------------------
template<int MODE>
__device__ __forceinline__ void gemm_core(const bf16* __restrict__ X,
                                          const bf16* __restrict__ Wt,
                                          const float* __restrict__ bias,
                                          void* __restrict__ outv,
                                          int m0, int n0, bf16* Al, bf16* Bl) {
    const int tid  = threadIdx.x;
    const int lane = tid & 63;
    const int w    = tid >> 6;
    const int wm   = (w & 1) * 64;
    const int wn   = (w >> 1) * 64;
    const int l15  = lane & 15;
    const int quad = lane >> 4;
    const int swz  = l15 & 7;          // read-side XOR swizzle (128B rows)

    f32x4 acc[4][4] = {};

    for (int kt = 0; kt < 1024; kt += 64) {
        __syncthreads();
        // stage 128 rows x 64 bf16 (128B) per tensor: 1024 16B chunks,
        // 4 per thread.  LDS dest is the wave-uniform chunk-group base
        // (HW scatters lane i to base + i*16); global src is per-lane
        // with e = (c&7)^(row&7) so the linear LDS image is XOR-swizzled.
        #pragma unroll
        for (int t = 0; t < 4; t++) {
            int c   = t * 256 + tid;          // this thread's chunk 0..1023
            int row = c >> 3;
            int e   = (c & 7) ^ (row & 7);
            bf16* la = &Al[(size_t)(t * 256 + w * 64) * 8];
            bf16* lb = &Bl[(size_t)(t * 256 + w * 64) * 8];
            gld16(&X [(size_t)(m0 + row) * 1024 + kt + e * 8], la);
            gld16(&Wt[(size_t)(n0 + row) * 1024 + kt + e * 8], lb);
        }
        __syncthreads();
        #pragma unroll
        for (int kk = 0; kk < 2; kk++) {
            bf16x8 a[4], b[4];
            #pragma unroll
            for (int i = 0; i < 4; i++)
                a[i] = *(const bf16x8*)&Al[(wm + i * 16 + l15) * 64 + ((kk * 4 + quad) ^ swz) * 8];
            #pragma unroll
            for (int j = 0; j < 4; j++)
                b[j] = *(const bf16x8*)&Bl[(wn + j * 16 + l15) * 64 + ((kk * 4 + quad) ^ swz) * 8];
            #pragma unroll
            for (int i = 0; i < 4; i++)
                #pragma unroll
                for (int j = 0; j < 4; j++)
                    acc[i][j] = __builtin_amdgcn_mfma_f32_16x16x32_bf16(a[i], b[j], acc[i][j], 0, 0, 0);
        }
    }

    float bv[4];
    #pragma unroll
    for (int j = 0; j < 4; j++) bv[j] = bias[n0 + wn + j * 16 + l15];

    #pragma unroll
    for (int i = 0; i < 4; i++) {
        int mbase = m0 + wm + i * 16 + quad * 4;
        #pragma unroll
        for (int j = 0; j < 4; j++) {
            int n = n0 + wn + j * 16 + l15;
            if (MODE == 2) {
                bf16* out = (bf16*)outv;
                int b = mbase >> 10, s = mbase & 1023;
                int h = n >> 6, d = n & 63;
                u16x4 pack;
                #pragma unroll
                for (int r = 0; r < 4; r++) {
                    bf16 v = (bf16)(acc[i][j][r] + bv[j]);
                    pack[r] = __builtin_bit_cast(u16, v);
                }
                *(u16x4*)&out[(((size_t)(b * 16 + h)) * 64 + d) * 1024 + s] = pack;
            } else if (MODE == 1) {
                bf16* out = (bf16*)outv;
                #pragma unroll
                for (int r = 0; r < 4; r++) {
                    int m = mbase + r;
                    int b = m >> 10, s = m & 1023;
                    int h = n >> 6, d = n & 63;
                    out[(((size_t)(b * 16 + h)) * 1024 + s) * 64 + d] =
                        (bf16)(acc[i][j][r] + bv[j]);
                }
            } else {
                float* out = (float*)outv;
                #pragma unroll
                for (int r = 0; r < 4; r++)
                    out[(size_t)(mbase + r) * 1024 + n] = acc[i][j][r] + bv[j];
            }
        }
    }
}

// Fused Q/K/V projections, compile-time epilogues: z=0 Q, z=1 K, z=2 V.
__global__ __launch_bounds__(256) void gemm_qkv(
        const bf16* __restrict__ Lb, const bf16* __restrict__ Xb,
        const bf16* __restrict__ Wqt, const bf16* __restrict__ Wkt,
        const bf16* __restrict__ Wvt,
        const float* __restrict__ bq, const float* __restrict__ bk,
        const float* __restrict__ bv,
        bf16* __restrict__ Qh, bf16* __restrict__ Kh, bf16* __restrict__ Vt) {
    __shared__ bf16 Al[128 * 64];
    __shared__ bf16 Bl[128 * 64];
    const int m0 = blockIdx.x * 128, n0 = blockIdx.y * 128;
    if (blockIdx.z == 0)      gemm_core<1>(Lb, Wqt, bq, Qh, m0, n0, Al, Bl);
    else if (blockIdx.z == 1) gemm_core<1>(Xb, Wkt, bk, Kh, m0, n0, Al, Bl);
    else                      gemm_core<2>(Xb, Wvt, bv, Vt, m0, n0, Al, Bl);
}

// Output projection (fp32 out)
__global__ __launch_bounds__(256) void gemm_o(
        const bf16* __restrict__ Ob, const bf16* __restrict__ Wot,
        const float* __restrict__ bo, float* __restrict__ out) {
    __shared__ bf16 Al[128 * 64];
    __shared__ bf16 Bl[128 * 64];
    gemm_core<0>(Ob, Wot, bo, out, blockIdx.x * 128, blockIdx.y * 128, Al, Bl);
}

// ---------------------------------------------------------------------------
// Flash attention, SWAPPED QK^T (T12), fixed-max softmax, deferred denom.
// Q,K: [bh][1024][64].  Vt: [bh][64][1024].  mask: [bh][1024][1024] i32.
// 1024 blocks (XCD-swizzled), 4 waves x 32 q-rows; 64 keys/iter, 16 iters.
//
// S^T = mfma(A=K_frag, B=Q_frag): output lane holds col=l15=q-row,
// row=quad*4+r=key.  Mask: one int4 per (rb,t); P store: ds_write_b64 into
// row-major P[q][key]; PV read side unchanged.
//
// Pipeline (T4): K/V triple-buffered, DMA 2 iters ahead; per-iter sync is
// s_waitcnt vmcnt(8) + raw s_barrier + sched_barrier(0).  Per-iter issue:
// [mask(it+1) 8 dwordx4] then [DMA(it+2) 8] -> at barrier the oldest-first
// vmcnt(8) retires {mask(it), DMA(it)} and floats DMA(it+1)'s 8 across.
// ---------------------------------------------------------------------------
__global__ __launch_bounds__(256, 2) void attn(const bf16* __restrict__ Q,
                                               const bf16* __restrict__ K,
                                               const bf16* __restrict__ Vt,
                                               const int*  __restrict__ mask,
                                               bf16* __restrict__ O) {
    __shared__ bf16 Kl[3][4096];     // [buf][key][64 d], 128B rows, swizzled
    __shared__ bf16 Vl[3][4096];     // [buf][d][64 k],   128B rows, swizzled
    __shared__ bf16 Pl[4][32 * 68];  // per-wave P [32 q][64 k], stride 68

    const int tid  = threadIdx.x;
    const int lane = tid & 63;
    const int w    = tid >> 6;
    const int l15  = lane & 15;
    const int quad = lane >> 4;

    // XCD-aware: blk&7 = xcd (presumed rr dispatch); 16 heads per xcd.
    const int blk = blockIdx.x;
    const int bh  = (blk & 7) * 16 + (blk >> 6);
    const int q0  = ((blk >> 3) & 7) * 128;
    const int qrow0 = q0 + w * 32;

    const bf16* Kbh = K  + (size_t)bh * 65536;
    const bf16* Vbh = Vt + (size_t)bh * 65536;
    // swapped layout: lane (quad,l15) reads mask row (qrow0+rb*16+l15),
    // cols kn + t*16 + quad*4 .. +3  -> int4
    const int* mbase = mask + ((size_t)bh * 1024 + qrow0 + l15) * 1024 + quad * 4;

    const int c0 = (w * 2 + 0) * 64 + lane;   // staging chunks (512 per tensor)
    const int c1 = (w * 2 + 1) * 64 + lane;
    const int swz = l15 & 7;                  // read-side XOR swizzle

    #define STAGE_KV(kk, buf)                                                          \
        {                                                                              \
            int r0 = c0 >> 3, e0 = (c0 & 7) ^ (r0 & 7);                                \
            int r1 = c1 >> 3, e1 = (c1 & 7) ^ (r1 & 7);                                \
            gld16(&Kbh[(size_t)((kk) + r0) * 64 + e0 * 8], &Kl[buf][(w * 2 + 0) * 512]); \
            gld16(&Kbh[(size_t)((kk) + r1) * 64 + e1 * 8], &Kl[buf][(w * 2 + 1) * 512]); \
            gld16(&Vbh[(size_t)r0 * 1024 + (kk) + e0 * 8], &Vl[buf][(w * 2 + 0) * 512]); \
            gld16(&Vbh[(size_t)r1 * 1024 + (kk) + e1 * 8], &Vl[buf][(w * 2 + 1) * 512]); \
        }

    // prologue (issue order matters for the counted waits):
    // [qa 4] [DMA(0) 8] [mask(0) 8] [DMA(1) 8]  -> barrier(0) vmcnt(8)
    bf16x8 qa[2][2];
    #pragma unroll
    for (int rb = 0; rb < 2; rb++) {
        const bf16* Qb = Q + ((size_t)bh * 1024 + qrow0 + rb * 16 + l15) * 64;
        qa[rb][0] = *(const bf16x8*)&Qb[quad * 8];
        qa[rb][1] = *(const bf16x8*)&Qb[32 + quad * 8];
    }
    STAGE_KV(0, 0);
    int4 mn4[2][4];
    #pragma unroll
    for (int rb = 0; rb < 2; rb++)
        #pragma unroll
        for (int t = 0; t < 4; t++)
            mn4[rb][t] = *(const int4*)&mbase[rb * 16 * 1024 + t * 16];
    STAGE_KV(64, 1);

    f32x4 o[2][4] = {};
    float lsum[2] = {};
    bf16* Pw = Pl[w];
    int cur = 0, stg = 2;

    for (int it = 0; it < 16; it++) {
        // counted-vmcnt barrier: retire DMA(it)+mask(it), float DMA(it+1)
        asm volatile("s_waitcnt vmcnt(8)" ::: "memory");
        __builtin_amdgcn_s_barrier();
        __builtin_amdgcn_sched_barrier(0);

        // compress arrived mask to nibbles (bit r), freeing prefetch regs
        int nib[2][4];
        #pragma unroll
        for (int rb = 0; rb < 2; rb++)
            #pragma unroll
            for (int t = 0; t < 4; t++)
                nib[rb][t] = (mn4[rb][t].x != 0) | ((mn4[rb][t].y != 0) << 1) |
                             ((mn4[rb][t].z != 0) << 2) | ((mn4[rb][t].w != 0) << 3);

        // mask prefetch for it+1 FIRST (wrapped on last iter: unused)
        {
            const int kn1 = ((it + 1) & 15) * 64;
            #pragma unroll
            for (int rb = 0; rb < 2; rb++)
                #pragma unroll
                for (int t = 0; t < 4; t++)
                    mn4[rb][t] = *(const int4*)&mbase[rb * 16 * 1024 + kn1 + t * 16];
        }
        // then K/V DMA for it+2 (wrapped on last two iters: unused)
        STAGE_KV(((it + 2) & 15) * 64, stg);

        const bf16* Kc = Kl[cur];
        const bf16* Vc = Vl[cur];

        // swapped QK^T: S^T[key][q] tiles; K-frag is A, Q-frag is B.
        f32x4 s[2][4];
        __builtin_amdgcn_s_setprio(1);
        #pragma unroll
        for (int t = 0; t < 4; t++) {
            bf16x8 kb0 = *(const bf16x8*)&Kc[(t * 16 + l15) * 64 + ((0 + quad) ^ swz) * 8];
            bf16x8 kb1 = *(const bf16x8*)&Kc[(t * 16 + l15) * 64 + ((4 + quad) ^ swz) * 8];
            #pragma unroll
            for (int rb = 0; rb < 2; rb++) {
                f32x4 z = {};
                z = __builtin_amdgcn_mfma_f32_16x16x32_bf16(kb0, qa[rb][0], z, 0, 0, 0);
                z = __builtin_amdgcn_mfma_f32_16x16x32_bf16(kb1, qa[rb][1], z, 0, 0, 0);
                s[rb][t] = z;
            }
        }
        __builtin_amdgcn_s_setprio(0);

        // p = exp2(s*0.125*log2e - 12*log2e)  == exp(s/8 - 12)
        // lane holds q-row l15, keys t*16+quad*4+r -> b64 P-row stores
        #pragma unroll
        for (int rb = 0; rb < 2; rb++)
            #pragma unroll
            for (int t = 0; t < 4; t++) {
                u16x4 pk;
                #pragma unroll
                for (int r = 0; r < 4; r++) {
                    float p = exp2f(fmaf(s[rb][t][r], 0.1803368801111204f,
                                         -17.312340490667565f));
                    p = ((nib[rb][t] >> r) & 1) ? p : 0.0f;
                    lsum[rb] += p;
                    pk[r] = __builtin_bit_cast(u16, (bf16)p);
                }
                *(u16x4*)&Pw[(rb * 16 + l15) * 68 + t * 16 + quad * 4] = pk;
            }

        // PV: P row-major [q][key] -> A-frag b128 reads (unchanged layout)
        bf16x8 pa[2][2];
        #pragma unroll
        for (int rb = 0; rb < 2; rb++) {
            pa[rb][0] = *(const bf16x8*)&Pw[(rb * 16 + l15) * 68 + quad * 8];
            pa[rb][1] = *(const bf16x8*)&Pw[(rb * 16 + l15) * 68 + 32 + quad * 8];
        }
        __builtin_amdgcn_s_setprio(1);
        #pragma unroll
        for (int nt = 0; nt < 4; nt++) {
            bf16x8 vb0 = *(const bf16x8*)&Vc[(nt * 16 + l15) * 64 + ((0 + quad) ^ swz) * 8];
            bf16x8 vb1 = *(const bf16x8*)&Vc[(nt * 16 + l15) * 64 + ((4 + quad) ^ swz) * 8];
            #pragma unroll
            for (int rb = 0; rb < 2; rb++) {
                o[rb][nt] = __builtin_amdgcn_mfma_f32_16x16x32_bf16(pa[rb][0], vb0, o[rb][nt], 0, 0, 0);
                o[rb][nt] = __builtin_amdgcn_mfma_f32_16x16x32_bf16(pa[rb][1], vb1, o[rb][nt], 0, 0, 0);
            }
        }
        __builtin_amdgcn_s_setprio(0);

        cur = (cur == 2) ? 0 : cur + 1;
        stg = (stg == 2) ? 0 : stg + 1;
    }
    #undef STAGE_KV

    // epilogue: quad-reduce denominators (q-row = l15), redistribute to the
    // C-layout rows (q-row = quad*4+r) via shfl, normalize, write.
    const int b = bh >> 4, h = bh & 15;
    #pragma unroll
    for (int rb = 0; rb < 2; rb++) {
        float l = lsum[rb];
        l += __shfl_xor(l, 16, 64);
        l += __shfl_xor(l, 32, 64);
        float inv = 1.0f / l;
        #pragma unroll
        for (int r = 0; r < 4; r++) {
            float invr = __shfl(inv, (lane & 48) | (quad * 4 + r), 64);
            int srow = qrow0 + rb * 16 + quad * 4 + r;
            bf16* orow = O + ((size_t)(b * 1024 + srow)) * 1024 + h * 64;
            #pragma unroll
            for (int nt = 0; nt < 4; nt++)
                orow[nt * 16 + l15] = (bf16)(o[rb][nt][r] * invr);
        }
    }
}

// ---------------------------------------------------------------------------
extern "C" void kernel_launch(void* const* d_in, const int* in_sizes, int n_in,
                              void* d_out, int out_size, void* d_ws, size_t ws_size,
                              hipStream_t stream) {
    const float* input  = (const float*)d_in[0];
    const float* latent = (const float*)d_in[1];
    const int*   mask   = (const int*)d_in[2];
    const float* Wq = (const float*)d_in[3];
    const float* bq = (const float*)d_in[4];
    const float* Wk = (const float*)d_in[5];
    const float* bk = (const float*)d_in[6];
    const float* Wv = (const float*)d_in[7];
    const float* bv = (const float*)d_in[8];
    const float* Wo = (const float*)d_in[9];
    const float* bo = (const float*)d_in[10];
    float* out = (float*)d_out;

    char* ws = (char*)d_ws;
    bf16* Xb  = (bf16*)(ws);                      // 16 MB  input  bf16
    bf16* Lb  = (bf16*)(ws + (16u << 20));        // 16 MB  latent bf16
    bf16* Qh  = (bf16*)(ws + (32u << 20));        // 16 MB  [bh][s][64]
    bf16* Kh  = (bf16*)(ws + (48u << 20));        // 16 MB  [bh][s][64]
    bf16* Vt  = (bf16*)(ws + (64u << 20));        // 16 MB  [bh][64][s]
    bf16* Ob  = (bf16*)(ws + (80u << 20));        // 16 MB  [8192][1024]
    bf16* Wqt = (bf16*)(ws + (96u << 20));
    bf16* Wkt = (bf16*)(ws + (98u << 20));
    bf16* Wvt = (bf16*)(ws + (100u << 20));
    bf16* Wot = (bf16*)(ws + (102u << 20));

    // fused convert + weight transpose
    prep<<<dim3(8192, 1, 1), 256, 0, stream>>>(
        input, latent, Xb, Lb, Wq, Wk, Wv, Wo, Wqt, Wkt, Wvt, Wot);

    // fused Q/K/V projection GEMMs (compile-time epilogues)
    gemm_qkv<<<dim3(64, 8, 3), 256, 0, stream>>>(
        Lb, Xb, Wqt, Wkt, Wvt, bq, bk, bv, Qh, Kh, Vt);

    attn<<<dim3(1024, 1, 1), 256, 0, stream>>>(Qh, Kh, Vt, mask, Ob);

    gemm_o<<<dim3(64, 8, 1), 256, 0, stream>>>(Ob, Wot, bo, out);
}